// Round 1
// baseline (3474.047 us; speedup 1.0000x reference)
//
#include <hip/hip_runtime.h>
#include <hip/hip_fp16.h>
#include <math.h>

#define NATOMS 40000
#define NEDGE  400000
#define NCRYS  400

// ---- workspace layout (float offsets) ----
#define O_W    0                       // weights[40000]
#define O_X    40960                   // x[40000*128] fp32
#define O_XCAT (O_X + 5120000)         // xcat[40000*512] fp16 (occupies 10,240,000 floats)
#define O_SUM  (O_XCAT + 10240000)     // summed[40000*128] fp32
#define O_STAT (O_SUM + 5120000)       // stats block [2048]
#define O_CRYS (O_STAT + 2048)         // crys[400*128]
// stat indices (within O_STAT)
#define S1SUM 0
#define S1SQ  256
#define SWE   512
#define S2SUM 516
#define S2SQ  644
// per-conv zero region = [0, 772)
#define SC1   772
#define SH1   1028
#define SC2   1284
#define SH2   1412
#define SWA   1540
#define SWC   1600

__device__ __forceinline__ float sp_f(float v) {
    return fmaxf(v, 0.f) + log1pf(expf(-fabsf(v)));
}
__device__ __forceinline__ float sig_f(float v) {
    return 1.f / (1.f + expf(-v));
}
__device__ __forceinline__ unsigned pack_h2(float a, float b) {
    __half2 h = __floats2half2_rn(a, b);
    return *reinterpret_cast<unsigned*>(&h);
}
__device__ __forceinline__ void ld4h(const __half* p, float* o) {
    int2 r = *reinterpret_cast<const int2*>(p);
    __half2 h0 = *reinterpret_cast<const __half2*>(&r.x);
    __half2 h1 = *reinterpret_cast<const __half2*>(&r.y);
    float2 f0 = __half22float2(h0), f1 = __half22float2(h1);
    o[0] = f0.x; o[1] = f0.y; o[2] = f1.x; o[3] = f1.y;
}

// ---- embedding: weights[a]=af[a][0]; x = af[:,1:] @ embW + embB ----
__global__ __launch_bounds__(128) void k_embed(const float* __restrict__ af,
        const float* __restrict__ embW, const float* __restrict__ embB,
        float* __restrict__ ws) {
    __shared__ float at[93 * 36];   // transposed: at[k*36+m], 32 atoms/block
    int a0 = blockIdx.x * 32;
    int tid = threadIdx.x;
    for (int p = tid; p < 32 * 93; p += 128) {
        int m = p / 93, k = p - m * 93;
        at[k * 36 + m] = af[(size_t)a0 * 93 + p];
    }
    __syncthreads();
    int cq = tid & 31;   // cols cq*4..+3
    int ag = tid >> 5;   // atoms ag*8..+7
    float acc[8][4];
    float4 bb = *reinterpret_cast<const float4*>(&embB[cq * 4]);
    #pragma unroll
    for (int m = 0; m < 8; m++) { acc[m][0] = bb.x; acc[m][1] = bb.y; acc[m][2] = bb.z; acc[m][3] = bb.w; }
    for (int k = 0; k < 92; k++) {
        float4 wv = *reinterpret_cast<const float4*>(&embW[k * 128 + cq * 4]);
        const float* arow = &at[(k + 1) * 36 + ag * 8];
        #pragma unroll
        for (int m = 0; m < 8; m++) {
            float av = arow[m];
            acc[m][0] += av * wv.x; acc[m][1] += av * wv.y;
            acc[m][2] += av * wv.z; acc[m][3] += av * wv.w;
        }
    }
    float* x = ws + O_X;
    #pragma unroll
    for (int m = 0; m < 8; m++) {
        int a = a0 + ag * 8 + m;
        *reinterpret_cast<float4*>(&x[(size_t)a * 128 + cq * 4]) =
            make_float4(acc[m][0], acc[m][1], acc[m][2], acc[m][3]);
    }
    if (tid < 32) ws[O_W + a0 + tid] = at[0 * 36 + tid];
    if (tid == 0) {
        float s = 0.f;
        for (int m = 0; m < 32; m++) s += at[0 * 36 + m];
        atomicAdd(&ws[O_STAT + SWA], s);
    }
}

// ---- xcat = x @ [Wa | Wb]  -> fp16 (per conv) ----
__global__ __launch_bounds__(256) void k_xcat(const float* __restrict__ Wi,
        float* __restrict__ ws) {
    __shared__ float xt[128 * 36];   // xt[k*36+m], 32 atoms
    const float* x = ws + O_X;
    __half* xcp = reinterpret_cast<__half*>(ws + O_XCAT);
    int a0 = blockIdx.x * 32;
    int tid = threadIdx.x;
    for (int p = tid * 4; p < 32 * 128; p += 1024) {
        float4 v = *reinterpret_cast<const float4*>(&x[(size_t)a0 * 128 + p]);
        int m = p >> 7, k = p & 127;
        xt[k * 36 + m] = v.x; xt[(k + 1) * 36 + m] = v.y;
        xt[(k + 2) * 36 + m] = v.z; xt[(k + 3) * 36 + m] = v.w;
    }
    __syncthreads();
    int cq = tid & 63, ag = tid >> 6;
    int hb = cq >> 5;            // 0: xa (rows 0..127), 1: xb (rows 128..255)
    int c0 = (cq & 31) * 8;      // col within half
    const float* Wp = Wi + (size_t)hb * 128 * 256;
    float acc[8][8];
    #pragma unroll
    for (int m = 0; m < 8; m++)
        #pragma unroll
        for (int j = 0; j < 8; j++) acc[m][j] = 0.f;
    for (int k = 0; k < 128; k++) {
        float4 w0 = *reinterpret_cast<const float4*>(&Wp[k * 256 + c0]);
        float4 w1 = *reinterpret_cast<const float4*>(&Wp[k * 256 + c0 + 4]);
        const float* xr = &xt[k * 36 + ag * 8];
        #pragma unroll
        for (int m = 0; m < 8; m++) {
            float xv = xr[m];
            acc[m][0] += xv * w0.x; acc[m][1] += xv * w0.y;
            acc[m][2] += xv * w0.z; acc[m][3] += xv * w0.w;
            acc[m][4] += xv * w1.x; acc[m][5] += xv * w1.y;
            acc[m][6] += xv * w1.z; acc[m][7] += xv * w1.w;
        }
    }
    #pragma unroll
    for (int m = 0; m < 8; m++) {
        int a = a0 + ag * 8 + m;
        uint4 pk;
        pk.x = pack_h2(acc[m][0], acc[m][1]);
        pk.y = pack_h2(acc[m][2], acc[m][3]);
        pk.z = pack_h2(acc[m][4], acc[m][5]);
        pk.w = pack_h2(acc[m][6], acc[m][7]);
        *reinterpret_cast<uint4*>(&xcp[(size_t)a * 512 + hb * 256 + c0]) = pk;
    }
}

// ---- edge pass: MODE 0 = weighted BN1 stats, MODE 1 = apply BN1 + msg + scatter ----
template<int MODE>
__global__ __launch_bounds__(256) void k_edge(const float* __restrict__ nbr,
        const int* __restrict__ eidx, const float* __restrict__ Wi,
        float* __restrict__ ws) {
    __shared__ float lds[4352];      // et[41*64]=2624 per tile; red[4096] at end (MODE0)
    __shared__ float wl[64];
    __shared__ int i0l[64], i1l[64];
    float* st = ws + O_STAT;
    float* summed = ws + O_SUM;
    const __half* xc = reinterpret_cast<const __half*>(ws + O_XCAT);
    int tid = threadIdx.x;
    int cq = tid & 31, eq = tid >> 5;

    float sF[4] = {0,0,0,0}, sC[4] = {0,0,0,0}, qF[4] = {0,0,0,0}, qC[4] = {0,0,0,0};
    float swe_acc = 0.f;
    float scf[4], shf[4], scc[4], shc[4];
    if (MODE == 1) {
        #pragma unroll
        for (int j = 0; j < 4; j++) {
            scf[j] = st[SC1 + cq * 4 + j];
            shf[j] = st[SH1 + cq * 4 + j];
            scc[j] = st[SC1 + 128 + cq * 4 + j];
            shc[j] = st[SH1 + 128 + cq * 4 + j];
        }
    }
    for (int g = 0; g < 5; ++g) {
        int tile = blockIdx.x + g * 1250;
        int e0 = tile * 64;
        __syncthreads();   // protect lds reuse from previous tile
        for (int q = tid; q < 672; q += 256) {
            float4 v = *reinterpret_cast<const float4*>(&nbr[(size_t)e0 * 42 + q * 4]);
            float va[4] = {v.x, v.y, v.z, v.w};
            #pragma unroll
            for (int j = 0; j < 4; j++) {
                int p = q * 4 + j;
                int m = p / 42;
                int k = p - m * 42;
                if (k < 41) lds[k * 64 + m] = va[j]; else wl[m] = va[j];
            }
        }
        if (tid < 64) {
            i0l[tid] = eidx[(size_t)(e0 + tid) * 2];
            i1l[tid] = eidx[(size_t)(e0 + tid) * 2 + 1];
        }
        __syncthreads();

        float ef[8][4], ec[8][4];
        #pragma unroll
        for (int m = 0; m < 8; m++)
            #pragma unroll
            for (int j = 0; j < 4; j++) { ef[m][j] = 0.f; ec[m][j] = 0.f; }
        for (int k = 0; k < 41; k++) {
            float4 wf = *reinterpret_cast<const float4*>(&Wi[(256 + k) * 256 + cq * 4]);
            float4 wc = *reinterpret_cast<const float4*>(&Wi[(256 + k) * 256 + 128 + cq * 4]);
            const float* ev = &lds[k * 64 + eq * 8];
            #pragma unroll
            for (int m = 0; m < 8; m++) {
                float e = ev[m];
                ef[m][0] += e * wf.x; ef[m][1] += e * wf.y;
                ef[m][2] += e * wf.z; ef[m][3] += e * wf.w;
                ec[m][0] += e * wc.x; ec[m][1] += e * wc.y;
                ec[m][2] += e * wc.z; ec[m][3] += e * wc.w;
            }
        }
        #pragma unroll
        for (int m = 0; m < 8; m++) {
            int em = eq * 8 + m;
            int i0 = i0l[em], i1 = i1l[em];
            float xaf[4], xac[4], xbf[4], xbc[4];
            ld4h(&xc[(size_t)i0 * 512 + cq * 4], xaf);
            ld4h(&xc[(size_t)i0 * 512 + 128 + cq * 4], xac);
            ld4h(&xc[(size_t)i1 * 512 + 256 + cq * 4], xbf);
            ld4h(&xc[(size_t)i1 * 512 + 384 + cq * 4], xbc);
            float gf[4], gc[4];
            #pragma unroll
            for (int j = 0; j < 4; j++) {
                gf[j] = ef[m][j] + xaf[j] + xbf[j];
                gc[j] = ec[m][j] + xac[j] + xbc[j];
            }
            if (MODE == 0) {
                float w = wl[em];
                #pragma unroll
                for (int j = 0; j < 4; j++) {
                    sF[j] += w * gf[j]; qF[j] += w * gf[j] * gf[j];
                    sC[j] += w * gc[j]; qC[j] += w * gc[j] * gc[j];
                }
            } else {
                #pragma unroll
                for (int j = 0; j < 4; j++) {
                    float fn = gf[j] * scf[j] + shf[j];
                    float cn = gc[j] * scc[j] + shc[j];
                    float msg = sig_f(fn) * sp_f(cn);
                    atomicAdd(&summed[(size_t)i0 * 128 + cq * 4 + j], msg);
                }
            }
        }
        if (MODE == 0 && tid == 0) {
            float s = 0.f;
            for (int m = 0; m < 64; m++) s += wl[m];
            swe_acc += s;
        }
    }
    if (MODE == 0) {
        __syncthreads();
        #pragma unroll
        for (int j = 0; j < 4; j++) {
            lds[eq * 512 + cq * 4 + j]       = sF[j];
            lds[eq * 512 + 128 + cq * 4 + j] = sC[j];
            lds[eq * 512 + 256 + cq * 4 + j] = qF[j];
            lds[eq * 512 + 384 + cq * 4 + j] = qC[j];
        }
        __syncthreads();
        for (int pos = tid; pos < 512; pos += 256) {
            float v = 0.f;
            #pragma unroll
            for (int q8 = 0; q8 < 8; q8++) v += lds[q8 * 512 + pos];
            atomicAdd(&st[pos], v);
        }
        if (tid == 0) atomicAdd(&st[SWE], swe_acc);
    }
}

__global__ void k_fin1(const float* __restrict__ bn1g, const float* __restrict__ bn1b,
        float* __restrict__ ws) {
    float* st = ws + O_STAT;
    int c = threadIdx.x;  // 256
    float sw = st[SWE];
    float mean = st[S1SUM + c] / sw;
    float var = st[S1SQ + c] / sw - mean * mean;
    float sc = bn1g[c] / sqrtf(var + 1e-5f);
    st[SC1 + c] = sc;
    st[SH1 + c] = bn1b[c] - mean * sc;
}

__global__ __launch_bounds__(256) void k_stats2(float* __restrict__ ws) {
    const float* sm = ws + O_SUM;
    const float* w = ws + O_W;
    float* st = ws + O_STAT;
    int tid = threadIdx.x;
    int c = tid & 127, r = tid >> 7;
    float s = 0.f, q = 0.f;
    for (int a = blockIdx.x * 2 + r; a < NATOMS; a += 512) {
        float wa = w[a];
        float v = sm[(size_t)a * 128 + c];
        s += wa * v; q += wa * v * v;
    }
    __shared__ float rs[256], rq[256];
    rs[tid] = s; rq[tid] = q;
    __syncthreads();
    if (r == 0) {
        atomicAdd(&st[S2SUM + c], s + rs[tid + 128]);
        atomicAdd(&st[S2SQ + c], q + rq[tid + 128]);
    }
}

__global__ void k_fin2(const float* __restrict__ bn2g, const float* __restrict__ bn2b,
        float* __restrict__ ws) {
    float* st = ws + O_STAT;
    int c = threadIdx.x;  // 128
    float sw = st[SWA];
    float mean = st[S2SUM + c] / sw;
    float var = st[S2SQ + c] / sw - mean * mean;
    float sc = bn2g[c] / sqrtf(var + 1e-5f);
    st[SC2 + c] = sc;
    st[SH2 + c] = bn2b[c] - mean * sc;
}

__global__ __launch_bounds__(256) void k_updx(float* __restrict__ ws) {
    float* x = ws + O_X;
    const float* sm = ws + O_SUM;
    const float* st = ws + O_STAT;
    int i = blockIdx.x * 256 + threadIdx.x;   // float4 index, 1,280,000 total
    int c4 = (i & 31) * 4;
    float4 xv = *reinterpret_cast<const float4*>(&x[(size_t)i * 4]);
    float4 sv = *reinterpret_cast<const float4*>(&sm[(size_t)i * 4]);
    float4 sc = *reinterpret_cast<const float4*>(&st[SC2 + c4]);
    float4 sh = *reinterpret_cast<const float4*>(&st[SH2 + c4]);
    float4 o;
    o.x = sp_f(xv.x + sv.x * sc.x + sh.x);
    o.y = sp_f(xv.y + sv.y * sc.y + sh.y);
    o.z = sp_f(xv.z + sv.z * sc.z + sh.z);
    o.w = sp_f(xv.w + sv.w * sc.w + sh.w);
    *reinterpret_cast<float4*>(&x[(size_t)i * 4]) = o;
}

__global__ void k_pool1(const int* __restrict__ cidx, float* __restrict__ ws) {
    int a = blockIdx.x * 256 + threadIdx.x;
    if (a < NATOMS) atomicAdd(&ws[O_STAT + SWC + cidx[a]], ws[O_W + a]);
}

__global__ void k_pool2(const int* __restrict__ cidx, float* __restrict__ ws) {
    int i = blockIdx.x * 256 + threadIdx.x;   // 5,120,000
    int a = i >> 7, c = i & 127;
    int s = cidx[a];
    float coef = ws[O_W + a] / ws[O_STAT + SWC + s];
    atomicAdd(&ws[O_CRYS + (size_t)s * 128 + c], coef * ws[O_X + (size_t)i]);
}

__global__ __launch_bounds__(256) void k_head(const float* __restrict__ fc1W,
        const float* __restrict__ fc1b, const float* __restrict__ fc2W,
        const float* __restrict__ fc2b, const float* __restrict__ outW,
        const float* __restrict__ outb, const float* __restrict__ ws,
        float* __restrict__ out) {
    __shared__ float spx[128], h1[256], h2[256], rr[4];
    int b = blockIdx.x, t = threadIdx.x;
    if (t < 128) spx[t] = sp_f(ws[O_CRYS + (size_t)b * 128 + t]);
    __syncthreads();
    float acc = fc1b[t];
    for (int k = 0; k < 128; k++) acc += spx[k] * fc1W[k * 256 + t];
    h1[t] = sp_f(acc);
    __syncthreads();
    acc = fc2b[t];
    for (int k = 0; k < 256; k++) acc += h1[k] * fc2W[k * 256 + t];
    h2[t] = sp_f(acc);
    __syncthreads();
    float p = h2[t] * outW[t];
    for (int off = 32; off > 0; off >>= 1) p += __shfl_down(p, off, 64);
    if ((t & 63) == 0) rr[t >> 6] = p;
    __syncthreads();
    if (t == 0) out[b] = rr[0] + rr[1] + rr[2] + rr[3] + outb[0];
}

extern "C" void kernel_launch(void* const* d_in, const int* in_sizes, int n_in,
                              void* d_out, int out_size, void* d_ws, size_t ws_size,
                              hipStream_t stream) {
    const float* af   = (const float*)d_in[0];
    const float* nbr  = (const float*)d_in[1];
    const int*   eidx = (const int*)d_in[2];
    const int*   cidx = (const int*)d_in[3];
    const float* embW = (const float*)d_in[4];
    const float* embB = (const float*)d_in[5];
    const float* convW= (const float*)d_in[6];
    // d_in[7] = conv_b: cancels exactly in the weighted BN that follows the conv GEMM
    const float* bn1g = (const float*)d_in[8];
    const float* bn1b = (const float*)d_in[9];
    const float* bn2g = (const float*)d_in[10];
    const float* bn2b = (const float*)d_in[11];
    const float* fc1W = (const float*)d_in[12];
    const float* fc1b = (const float*)d_in[13];
    const float* fc2W = (const float*)d_in[14];
    const float* fc2b = (const float*)d_in[15];
    const float* outW = (const float*)d_in[16];
    const float* outb = (const float*)d_in[17];
    float* ws = (float*)d_ws;
    float* out = (float*)d_out;

    // zero: stats block (incl. sw_atom, sw_crys) + crys
    hipMemsetAsync(ws + O_STAT, 0, (size_t)(2048 + 51200) * sizeof(float), stream);
    k_embed<<<1250, 128, 0, stream>>>(af, embW, embB, ws);
    k_pool1<<<157, 256, 0, stream>>>(cidx, ws);

    for (int i = 0; i < 3; i++) {
        hipMemsetAsync(ws + O_SUM, 0, (size_t)5120000 * sizeof(float), stream);
        hipMemsetAsync(ws + O_STAT, 0, (size_t)772 * sizeof(float), stream);
        const float* Wi = convW + (size_t)i * 297 * 256;
        k_xcat<<<1250, 256, 0, stream>>>(Wi, ws);
        k_edge<0><<<1250, 256, 0, stream>>>(nbr, eidx, Wi, ws);
        k_fin1<<<1, 256, 0, stream>>>(bn1g + i * 256, bn1b + i * 256, ws);
        k_edge<1><<<1250, 256, 0, stream>>>(nbr, eidx, Wi, ws);
        k_stats2<<<256, 256, 0, stream>>>(ws);
        k_fin2<<<1, 128, 0, stream>>>(bn2g + i * 128, bn2b + i * 128, ws);
        k_updx<<<5000, 256, 0, stream>>>(ws);
    }
    k_pool2<<<20000, 256, 0, stream>>>(cidx, ws);
    k_head<<<400, 256, 0, stream>>>(fc1W, fc1b, fc2W, fc2b, outW, outb, ws, out);
}